// Round 6
// baseline (43.680 us; speedup 1.0000x reference)
//
#include <hip/hip_runtime.h>
#include <hip/hip_bf16.h>
#include <cstdint>

// ExemplarAttention: logits[b,c] = gamma * log( sum_{n: label[n]=c} exp(-beta * d[b,n]) + eps )
// d[b,n] = x2w[b] + e2w[n] - 2 * sum_k (x[b,k]*w[k]) * E[n,k]
//
// Round 6: 8-phase schedule (T3+T4+T5) on the 256x256/BK=64/8-wave/128KB-dbuf geometry.
// Per K-step: 4 phases, each {ds_read quadrant frags, 2x global_load_lds (next buffer),
// raw s_barrier, setprio(1), 16 MFMA, setprio(0), s_barrier}; vmcnt(0) drain only at the
// K-tile boundary. Compiler handles lgkmcnt for ds_read->MFMA (guide: fine-grained).
// Also merged the two prep_rows launches into one grid (one less serial launch).

typedef __attribute__((ext_vector_type(4))) float f32x4;
typedef __attribute__((ext_vector_type(8))) __bf16 bf16x8;
typedef __attribute__((ext_vector_type(4))) _Float16 half4;
typedef __attribute__((ext_vector_type(4))) unsigned int u32x4;

#define DDIM 512
#define NC 10
#define NCP 16
#define NECH 64    // exemplar chunks (16384/256)
#define EPSF 1e-9f

#define BAR()    asm volatile("s_barrier" ::: "memory")
#define WAITV0() asm volatile("s_waitcnt vmcnt(0)" ::: "memory")

typedef const __attribute__((address_space(1))) void* gas_ptr;
typedef __attribute__((address_space(3))) void* las_ptr;

__device__ inline void async16(const void* g, void* l) {
  __builtin_amdgcn_global_load_lds((gas_ptr)g, (las_ptr)l, 16, 0, 0);
}

__device__ inline unsigned short f2bf(float f) {
  unsigned int u = __float_as_uint(f);
  u += 0x7FFFu + ((u >> 16) & 1u);   // round-to-nearest-even
  return (unsigned short)(u >> 16);
}

__device__ inline float wave_sum(float v) {
  #pragma unroll
  for (int o = 32; o > 0; o >>= 1) v += __shfl_xor(v, o, 64);
  return v;
}

__device__ inline float softplus(float x) {
  return (x > 20.0f) ? x : log1pf(__expf(x));
}

// ---- kernel 1: w = softmax(w_u)+eps ; scal = {beta, gamma} -------------------
__global__ void prep_w(const float* __restrict__ wu, const float* __restrict__ gu,
                       const float* __restrict__ bu, float* __restrict__ w,
                       float* __restrict__ scal) {
  __shared__ float sm[16];
  int t = threadIdx.x, lane = t & 63, wd = t >> 6;
  float v = wu[t];
  float m = v;
  #pragma unroll
  for (int o = 32; o > 0; o >>= 1) m = fmaxf(m, __shfl_xor(m, o, 64));
  if (lane == 0) sm[wd] = m;
  __syncthreads();
  float mm = sm[0];
  #pragma unroll
  for (int i = 1; i < 8; ++i) mm = fmaxf(mm, sm[i]);
  float e = __expf(v - mm);
  float s = wave_sum(e);
  if (lane == 0) sm[8 + wd] = s;
  __syncthreads();
  float ss = 0.f;
  #pragma unroll
  for (int i = 0; i < 8; ++i) ss += sm[8 + i];
  w[t] = e / ss + EPSF;
  if (t == 0) {
    scal[0] = softplus(bu[0]) + EPSF;   // beta
    scal[1] = softplus(gu[0]) + EPSF;   // gamma
  }
}

// ---- kernel 2: per-row bf16 cast + weighted square sum (x AND ex in one grid) ----
__global__ void prep_rows2(const float* __restrict__ x, const float* __restrict__ ex,
                           const float* __restrict__ w,
                           unsigned short* __restrict__ xbf, unsigned short* __restrict__ ebf,
                           float* __restrict__ x2w, float* __restrict__ e2w, int nxb) {
  int lane = threadIdx.x & 63, wd = threadIdx.x >> 6;
  const float* in; unsigned short* obf; float* osq; int mulw; size_t row;
  if (blockIdx.x < (unsigned)nxb) {
    in = x; obf = xbf; osq = x2w; mulw = 1;
    row = (size_t)blockIdx.x * 4 + wd;
  } else {
    in = ex; obf = ebf; osq = e2w; mulw = 0;
    row = (size_t)(blockIdx.x - nxb) * 4 + wd;
  }
  const float* p = in + row * DDIM + lane * 8;
  const float* pw = w + lane * 8;
  float4 va = *(const float4*)(p);
  float4 vb = *(const float4*)(p + 4);
  float4 wa = *(const float4*)(pw);
  float4 wb = *(const float4*)(pw + 4);
  float s = va.x * va.x * wa.x + va.y * va.y * wa.y + va.z * va.z * wa.z + va.w * va.w * wa.w
          + vb.x * vb.x * wb.x + vb.y * vb.y * wb.y + vb.z * vb.z * wb.z + vb.w * vb.w * wb.w;
  unsigned short o[8];
  if (mulw) {
    o[0] = f2bf(va.x * wa.x); o[1] = f2bf(va.y * wa.y);
    o[2] = f2bf(va.z * wa.z); o[3] = f2bf(va.w * wa.w);
    o[4] = f2bf(vb.x * wb.x); o[5] = f2bf(vb.y * wb.y);
    o[6] = f2bf(vb.z * wb.z); o[7] = f2bf(vb.w * wb.w);
  } else {
    o[0] = f2bf(va.x); o[1] = f2bf(va.y); o[2] = f2bf(va.z); o[3] = f2bf(va.w);
    o[4] = f2bf(vb.x); o[5] = f2bf(vb.y); o[6] = f2bf(vb.z); o[7] = f2bf(vb.w);
  }
  u32x4 pk;
  pk[0] = (unsigned)o[0] | ((unsigned)o[1] << 16);
  pk[1] = (unsigned)o[2] | ((unsigned)o[3] << 16);
  pk[2] = (unsigned)o[4] | ((unsigned)o[5] << 16);
  pk[3] = (unsigned)o[6] | ((unsigned)o[7] << 16);
  *(u32x4*)(obf + row * DDIM + lane * 8) = pk;
  s = wave_sum(s);
  if (lane == 0) osq[row] = s;
}

// ---- kernel 3: fused GEMM + exp + class partial reduce ----------------------
// grid: 256 blocks (64 exemplar tiles x 4 batch tiles), 512 threads = 8 waves.
// Wave (wid>>2) = exemplar half (128 rows), (wid&3) = batch quarter (64 cols).
// part layout: part[b_global][echunk][NCP], echunk in [0,64).
__global__ __launch_bounds__(512, 2) void gemm_fused(
    const unsigned short* __restrict__ Ebf, const unsigned short* __restrict__ Xbf,
    const int* __restrict__ labels, const float* __restrict__ x2w,
    const float* __restrict__ e2w, const float* __restrict__ scal,
    float* __restrict__ part) {
  // 2 buffers x (E 32KB | X 32KB) = 128KB; within a buffer X at +16384 shorts.
  __shared__ __attribute__((aligned(16))) unsigned short smem[2 * 2 * 16384];
  __shared__ int lab[256];
  const int tid = threadIdx.x, lane = tid & 63, wid = tid >> 6;

  // XCD-aware bijective swizzle: 256 blocks, XCD x gets E-tiles [x*8, x*8+8) x 4 b-tiles.
  const int orig = blockIdx.x;          // 0..255
  const int xcd = orig & 7;
  const int local = orig >> 3;          // 0..31
  const int be = xcd * 8 + (local >> 2);   // exemplar tile 0..63
  const int bb = local & 3;                // batch tile 0..3

  if (tid < 256) lab[tid] = labels[be * 256 + tid];

  // --- staging: 4 calls per operand per K-step, 512 thr x 16B = 8KB/call ---
  // i = c*512 + tid in [0,2048): row = i>>3 (256 rows), ch = i&7 (16B units in 128B row).
  // LDS linear (global_load_lds constraint); SOURCE pre-swizzled so that LDS (row,ch)
  // holds global (row, ch^(row&7)).
  const unsigned short* srcE[4];
  const unsigned short* srcX[4];
  int loff[4];
  #pragma unroll
  for (int c = 0; c < 4; ++c) {
    int i = c * 512 + tid;
    int row = i >> 3, ch = i & 7;
    int sch = ch ^ (row & 7);
    srcE[c] = Ebf + (size_t)(be * 256 + row) * DDIM + sch * 8;
    srcX[c] = Xbf + (size_t)(bb * 256 + row) * DDIM + sch * 8;
    loff[c] = i * 8;   // element offset within operand block
  }

  const int WE = (wid >> 2) * 128;   // exemplar base (0 or 128)
  const int WB = (wid & 3) * 64;     // batch base (0,64,128,192)

  // --- fragment read byte-offsets within operand block (ks=0); ks=1 = ^64 ---
  int eoff[8], xoff[4];
  {
    const int ch = lane >> 4;   // 0..3
    #pragma unroll
    for (int f = 0; f < 8; ++f) {
      int erow = WE + f * 16 + (lane & 15);
      eoff[f] = erow * 128 + ((ch ^ (erow & 7)) * 16);
    }
    #pragma unroll
    for (int f = 0; f < 4; ++f) {
      int xrow = WB + f * 16 + (lane & 15);
      xoff[f] = xrow * 128 + ((ch ^ (xrow & 7)) * 16);
    }
  }

  // prologue: stage K-tile 0 into buffer 0
  #pragma unroll
  for (int c = 0; c < 4; ++c) {
    async16(srcE[c], &smem[loff[c]]);
    async16(srcX[c], &smem[16384 + loff[c]]);
    srcE[c] += 64; srcX[c] += 64;
  }
  __syncthreads();   // full drain -> buffer 0 ready

  f32x4 acc[8][4] = {};
  int cur = 0;

#define DSE(F, KS) (*(const bf16x8*)(bE + (eoff[F] ^ ((KS) << 6))))
#define DSX(F, KS) (*(const bf16x8*)(bX + (xoff[F] ^ ((KS) << 6))))
#define MFMA(A, B, C) __builtin_amdgcn_mfma_f32_16x16x32_bf16((A), (B), (C), 0, 0, 0)

  for (int kt = 0; kt < 8; ++kt) {
    const int nb = (cur ^ 1) * 32768;              // short units
    const char* bE = (const char*)smem + cur * 65536;
    const char* bX = bE + 32768;
    bf16x8 ef[4][2], xf[2][2];

    // ---- phase 0: quadrant (E-half 0, B-pair 0) ----
    #pragma unroll
    for (int f = 0; f < 4; ++f) { ef[f][0] = DSE(f, 0); ef[f][1] = DSE(f, 1); }
    #pragma unroll
    for (int f = 0; f < 2; ++f) { xf[f][0] = DSX(f, 0); xf[f][1] = DSX(f, 1); }
    if (kt < 7) {
      async16(srcE[0], &smem[nb + loff[0]]);
      async16(srcX[0], &smem[nb + 16384 + loff[0]]);
      srcE[0] += 64; srcX[0] += 64;
    }
    BAR();
    __builtin_amdgcn_s_setprio(1);
    #pragma unroll
    for (int ks = 0; ks < 2; ++ks)
      #pragma unroll
      for (int fe = 0; fe < 4; ++fe)
        #pragma unroll
        for (int fb = 0; fb < 2; ++fb)
          acc[fe][fb] = MFMA(ef[fe][ks], xf[fb][ks], acc[fe][fb]);
    __builtin_amdgcn_s_setprio(0);
    BAR();

    // ---- phase 1: quadrant (E-half 0, B-pair 1) ----
    #pragma unroll
    for (int f = 0; f < 2; ++f) { xf[f][0] = DSX(2 + f, 0); xf[f][1] = DSX(2 + f, 1); }
    if (kt < 7) {
      async16(srcE[1], &smem[nb + loff[1]]);
      async16(srcX[1], &smem[nb + 16384 + loff[1]]);
      srcE[1] += 64; srcX[1] += 64;
    }
    BAR();
    __builtin_amdgcn_s_setprio(1);
    #pragma unroll
    for (int ks = 0; ks < 2; ++ks)
      #pragma unroll
      for (int fe = 0; fe < 4; ++fe)
        #pragma unroll
        for (int fb = 0; fb < 2; ++fb)
          acc[fe][2 + fb] = MFMA(ef[fe][ks], xf[fb][ks], acc[fe][2 + fb]);
    __builtin_amdgcn_s_setprio(0);
    BAR();

    // ---- phase 2: quadrant (E-half 1, B-pair 0) ----
    #pragma unroll
    for (int f = 0; f < 4; ++f) { ef[f][0] = DSE(4 + f, 0); ef[f][1] = DSE(4 + f, 1); }
    #pragma unroll
    for (int f = 0; f < 2; ++f) { xf[f][0] = DSX(f, 0); xf[f][1] = DSX(f, 1); }
    if (kt < 7) {
      async16(srcE[2], &smem[nb + loff[2]]);
      async16(srcX[2], &smem[nb + 16384 + loff[2]]);
      srcE[2] += 64; srcX[2] += 64;
    }
    BAR();
    __builtin_amdgcn_s_setprio(1);
    #pragma unroll
    for (int ks = 0; ks < 2; ++ks)
      #pragma unroll
      for (int fe = 0; fe < 4; ++fe)
        #pragma unroll
        for (int fb = 0; fb < 2; ++fb)
          acc[4 + fe][fb] = MFMA(ef[fe][ks], xf[fb][ks], acc[4 + fe][fb]);
    __builtin_amdgcn_s_setprio(0);
    BAR();

    // ---- phase 3: quadrant (E-half 1, B-pair 1) ----
    #pragma unroll
    for (int f = 0; f < 2; ++f) { xf[f][0] = DSX(2 + f, 0); xf[f][1] = DSX(2 + f, 1); }
    if (kt < 7) {
      async16(srcE[3], &smem[nb + loff[3]]);
      async16(srcX[3], &smem[nb + 16384 + loff[3]]);
      srcE[3] += 64; srcX[3] += 64;
    }
    BAR();
    __builtin_amdgcn_s_setprio(1);
    #pragma unroll
    for (int ks = 0; ks < 2; ++ks)
      #pragma unroll
      for (int fe = 0; fe < 4; ++fe)
        #pragma unroll
        for (int fb = 0; fb < 2; ++fb)
          acc[4 + fe][2 + fb] = MFMA(ef[fe][ks], xf[fb][ks], acc[4 + fe][2 + fb]);
    __builtin_amdgcn_s_setprio(0);

    // ---- K-tile boundary: next buffer's loads must have landed ----
    WAITV0();
    BAR();
    cur ^= 1;
  }
#undef DSE
#undef DSX
#undef MFMA

  // epilogue: sim = exp(-beta*(x2w + e2w - 2*cross)); class-reduce via one-hot MFMA.
  const float beta = scal[0];
  const int rb = (lane >> 4) * 4;   // row base within 16x16 fragment
  const int col = lane & 15;        // batch col in acc frags; class in cs frags
  float e2v[8][4];
  #pragma unroll
  for (int fe = 0; fe < 8; ++fe)
    #pragma unroll
    for (int r = 0; r < 4; ++r)
      e2v[fe][r] = e2w[be * 256 + WE + fe * 16 + rb + r];
  half4 oh[8];
  #pragma unroll
  for (int fe = 0; fe < 8; ++fe)
    #pragma unroll
    for (int i = 0; i < 4; ++i)
      oh[fe][i] = (lab[WE + fe * 16 + rb + i] == col) ? (_Float16)1.0f : (_Float16)0.0f;

  f32x4 csv[4];
  #pragma unroll
  for (int fb = 0; fb < 4; ++fb) {
    const float xv = x2w[bb * 256 + WB + fb * 16 + col];
    f32x4 cs = {0.f, 0.f, 0.f, 0.f};
    #pragma unroll
    for (int fe = 0; fe < 8; ++fe) {
      half4 sa;
      #pragma unroll
      for (int r = 0; r < 4; ++r)
        sa[r] = (_Float16)__expf(-beta * (xv + e2v[fe][r] - 2.0f * acc[fe][fb][r]));
      cs = __builtin_amdgcn_mfma_f32_16x16x16f16(sa, oh[fe], cs, 0, 0, 0);
    }
    csv[fb] = cs;   // cs[r]: class-sum for batch row (WB+fb*16+rb+r), class=col
  }

  // intra-block combine of the two exemplar halves via LDS (reuse smem, 32KB):
  // red[half][brow_local 256][16], half = WE>>7.
  __syncthreads();   // ensure all waves past K-loop reads before repurposing smem
  float* red = (float*)smem;
  const int half = WE >> 7;
  #pragma unroll
  for (int fb = 0; fb < 4; ++fb)
    #pragma unroll
    for (int r = 0; r < 4; ++r)
      red[(((half << 8) | (WB + fb * 16 + rb + r)) << 4) | col] = csv[fb][r];
  __syncthreads();

  // sum halves, store block partial (256 x 16 f32) with aligned float4 stores.
  {
    const int o = tid * 8;        // 0..4095
    const int rl = o >> 4;        // brow_local 0..255
    const int c0 = o & 15;        // 0 or 8
    const float4* p0 = (const float4*)&red[(rl << 4) | c0];
    const float4* p1 = (const float4*)&red[((256 | rl) << 4) | c0];
    float4 a0 = p0[0], a1 = p0[1], b0 = p1[0], b1 = p1[1];
    float4 r0 = {a0.x + b0.x, a0.y + b0.y, a0.z + b0.z, a0.w + b0.w};
    float4 r1 = {a1.x + b1.x, a1.y + b1.y, a1.z + b1.z, a1.w + b1.w};
    float* g = &part[(((size_t)(bb * 256 + rl)) * NECH + be) * NCP + c0];
    *(float4*)g = r0;
    *(float4*)(g + 4) = r1;
  }
}

// ---- kernel 4: logits = gamma * log( sum_ne part[b][ne][c] + eps ) ----------
__global__ __launch_bounds__(256) void reduce_logits(
    const float* __restrict__ part, const float* __restrict__ scal,
    float* __restrict__ out) {
  const int lane = threadIdx.x & 63, wd = threadIdx.x >> 6;
  const int b = blockIdx.x * 4 + wd;
  const int cl = lane & 15, ch0 = lane >> 4;
  const float* p = part + (size_t)b * NECH * NCP;
  float v = 0.f;
  #pragma unroll
  for (int k = 0; k < 16; ++k)
    v += p[(ch0 + 4 * k) * NCP + cl];
  v += __shfl_xor(v, 16, 64);
  v += __shfl_xor(v, 32, 64);
  if (lane < NC) out[b * NC + lane] = scal[1] * logf(v + EPSF);
}

extern "C" void kernel_launch(void* const* d_in, const int* in_sizes, int n_in,
                              void* d_out, int out_size, void* d_ws, size_t ws_size,
                              hipStream_t stream) {
  const float* x  = (const float*)d_in[0];
  const float* ex = (const float*)d_in[1];
  const int* labels = (const int*)d_in[2];
  const float* wu = (const float*)d_in[3];
  const float* gu = (const float*)d_in[4];
  const float* bu = (const float*)d_in[5];
  float* out = (float*)d_out;
  const int B = in_sizes[0] / DDIM;   // 1024
  const int N = in_sizes[2];          // 16384

  char* ws = (char*)d_ws;
  const size_t off_scal = 0;
  const size_t off_w    = 256;
  const size_t off_x2w  = 4096;
  const size_t off_e2w  = off_x2w + (size_t)B * 4;
  const size_t off_xbf  = off_e2w + (size_t)N * 4;
  const size_t off_ebf  = off_xbf + (size_t)B * DDIM * 2;
  const size_t off_part = off_ebf + (size_t)N * DDIM * 2;
  const size_t need     = off_part + (size_t)B * NECH * NCP * 4;
  if (ws_size < need) return;   // insufficient scratch; fail loudly (zeros)

  float* scal = (float*)(ws + off_scal);
  float* w    = (float*)(ws + off_w);
  float* x2w  = (float*)(ws + off_x2w);
  float* e2w  = (float*)(ws + off_e2w);
  unsigned short* xbf = (unsigned short*)(ws + off_xbf);
  unsigned short* ebf = (unsigned short*)(ws + off_ebf);
  float* part = (float*)(ws + off_part);

  prep_w<<<1, DDIM, 0, stream>>>(wu, gu, bu, w, scal);
  prep_rows2<<<(B + N) / 4, 256, 0, stream>>>(x, ex, w, xbf, ebf, x2w, e2w, B / 4);
  gemm_fused<<<(N / 256) * (B / 256), 512, 0, stream>>>(ebf, xbf, labels, x2w, e2w, scal, part);
  reduce_logits<<<B / 4, 256, 0, stream>>>(part, scal, out);
}